// Round 4
// baseline (65.372 us; speedup 1.0000x reference)
//
#include <hip/hip_runtime.h>

// DynamicMaskHead: bf16-MFMA with pre-packed params + LDS-staged x.
// Block = 256 threads = 4 waves = one 256-px image row. x (256px x 64ch)
// is staged once per block into 32KB of XOR-swizzled bf16 LDS; each wave
// computes all 256 px for its instance subset, so packed-param loads are
// amortized 4x better than the register-resident-x version.
//
// Swizzle: lds byte = px*128 + chbyte, chbyte ^= ((px&7)<<4).
//   fill: lane writes b128 (8ch) for px=tid -> slots (c8 ^ (px&7)): 8 lanes
//         per 4-bank group = LDS write floor, conflict-free.
//   read: lane (g,col) reads b128 at px=nt*16+col, chunk c -> slots
//         ((c<<2|g) ^ (col&7)): 2 lanes per slot = free.
// K-consistency fragment trick + C/D layout as verified in rounds 2-3
// (absmax 0.03125). Row-uniform y folds wy*yf into the bias per instance.

#define CIN  64
#define HH   160
#define WW   256
#define HWSZ (HH * WW)
#define PP   1361
#define MASK_BIAS_SHIFT 2.19f
#define PKF  2112              // floats per instance in packed buffer
#define NSPLIT 2               // instance split across gridDim.z

typedef short short8 __attribute__((ext_vector_type(8)));
typedef float f32x4  __attribute__((ext_vector_type(4)));

union BF8 { short8 s; __bf16 b[8]; };

// packed float offsets within one instance's PKF block:
//   0: a0 chunk0 (64 x short8)   256: a0 chunk1   512: a1 (64 x short8)
//   768: wx (64 x f32x4)  1024: wy  1280: b0  1536: b1  1792: w2  2048: b2

__global__ __launch_bounds__(64) void prep_params(
    const float* __restrict__ params, float* __restrict__ pk)
{
    const int t    = blockIdx.x;
    const int lane = threadIdx.x;
    const int col  = lane & 15;
    const int g    = lane >> 4;
    const float* pw = params + (size_t)t * PP;
    float* dst = pk + (size_t)t * PKF;

    BF8 a00, a01, a1;
#pragma unroll
    for (int j = 0; j < 8; ++j) {
        a00.b[j] = (__bf16)pw[col * 66 + 2 +      g * 8 + j];
        a01.b[j] = (__bf16)pw[col * 66 + 2 + 32 + g * 8 + j];
    }
#pragma unroll
    for (int j = 0; j < 4; ++j) {
        a1.b[j]     = (__bf16)pw[1056 + col * 16 + g * 4 + j];
        a1.b[4 + j] = (__bf16)0.f;
    }
    ((short8*)(dst      ))[lane] = a00.s;
    ((short8*)(dst + 256))[lane] = a01.s;
    ((short8*)(dst + 512))[lane] = a1.s;

    f32x4 wx, wy, b0, b1, w2;
#pragma unroll
    for (int j = 0; j < 4; ++j) {
        const int r = g * 4 + j;
        wx[j] = pw[r * 66 + 0];
        wy[j] = pw[r * 66 + 1];
        b0[j] = pw[1328 + r];
        b1[j] = pw[1344 + r];
        w2[j] = pw[1312 + r];
    }
    ((f32x4*)(dst +  768))[lane] = wx;
    ((f32x4*)(dst + 1024))[lane] = wy;
    ((f32x4*)(dst + 1280))[lane] = b0;
    ((f32x4*)(dst + 1536))[lane] = b1;
    ((f32x4*)(dst + 1792))[lane] = w2;
    if (lane == 0) dst[2048] = pw[1360] - MASK_BIAS_SHIFT;
}

__global__ __launch_bounds__(256, 4) void mask_head_lds(
    const float* __restrict__ x,
    const float* __restrict__ pk,
    const int*   __restrict__ num_ins,
    float*       __restrict__ out,
    int N, int T)
{
    __shared__ __align__(16) char xs[256 * CIN * 2];   // [px][ch] bf16, swizzled

    const int tid  = threadIdx.x;
    const int wave = tid >> 6;
    const int lane = tid & 63;
    const int col  = lane & 15;
    const int g    = lane >> 4;
    const int n    = blockIdx.y;
    const int s    = blockIdx.z;
    const int blockpx = blockIdx.x * 256;   // one full image row (WW==256)

    // ---- stage x into LDS: thread owns px = tid, 64 ch in groups of 8
    {
        const float* xb = x + (size_t)n * CIN * HWSZ + blockpx + tid;
        const int swz = (tid & 7) << 4;
        char* dst = xs + tid * 128;
        for (int c8 = 0; c8 < 8; ++c8) {
            BF8 v;
#pragma unroll
            for (int j = 0; j < 8; ++j)
                v.b[j] = (__bf16)xb[(size_t)(c8 * 8 + j) * HWSZ];
            *(short8*)(dst + ((c8 * 16) ^ swz)) = v.s;
        }
    }
    __syncthreads();

    // instance range for this image (repeat-pad on last image)
    int t0 = 0;
    for (int j = 0; j < n; ++j) t0 += num_ins[j];
    int t1 = t0 + num_ins[n];
    if (n == N - 1) t1 = T;
    if (t1 > T) t1 = T;
    const int M = t1 - t0;

    const float yf   = (float)blockIdx.x;   // row-uniform y coordinate
    const float colf = (float)col;

    for (int m = s + NSPLIT * wave; m < M; m += NSPLIT * 4) {
        const int t = t0 + m;
        const float* pt = pk + (size_t)t * PKF;

        short8 a00 = ((const short8*)(pt      ))[lane];
        short8 a01 = ((const short8*)(pt + 256))[lane];
        short8 a1  = ((const short8*)(pt + 512))[lane];
        f32x4  wxv = ((const f32x4*)(pt +  768))[lane];
        f32x4  wyv = ((const f32x4*)(pt + 1024))[lane];
        f32x4  b0v = ((const f32x4*)(pt + 1280))[lane];
        f32x4  b1v = ((const f32x4*)(pt + 1536))[lane];
        f32x4  w2v = ((const f32x4*)(pt + 1792))[lane];
        const float b2v = pt[2048];

        f32x4 bb;                      // fold wy*y into bias (y block-uniform)
#pragma unroll
        for (int j = 0; j < 4; ++j) bb[j] = fmaf(wyv[j], yf, b0v[j]);

        float oval = 0.f;
#pragma unroll
        for (int nt = 0; nt < 16; ++nt) {
            const int px   = nt * 16 + col;
            const int rswz = (px & 7) << 4;
            const char* src = xs + px * 128;
            short8 xb0 = *(const short8*)(src + ((      g * 16) ^ rswz));
            short8 xb1 = *(const short8*)(src + ((64 + g * 16) ^ rswz));

            f32x4 acc0 = {0.f, 0.f, 0.f, 0.f};
            acc0 = __builtin_amdgcn_mfma_f32_16x16x32_bf16(a00, xb0, acc0, 0, 0, 0);
            acc0 = __builtin_amdgcn_mfma_f32_16x16x32_bf16(a01, xb1, acc0, 0, 0, 0);

            const float xf = colf + (float)(nt * 16);
            BF8 h0;
#pragma unroll
            for (int j = 0; j < 4; ++j) {
                float v = acc0[j] + bb[j];
                v = fmaf(wxv[j], xf, v);
                v = fmaxf(v, 0.f);
                h0.b[j]     = (__bf16)v;
                h0.b[4 + j] = (__bf16)0.f;
            }

            f32x4 acc1 = {0.f, 0.f, 0.f, 0.f};
            acc1 = __builtin_amdgcn_mfma_f32_16x16x32_bf16(a1, h0.s, acc1, 0, 0, 0);

            float sum = 0.f;
#pragma unroll
            for (int j = 0; j < 4; ++j) {
                const float h = fmaxf(acc1[j] + b1v[j], 0.f);
                sum = fmaf(w2v[j], h, sum);
            }
            sum += __shfl_xor(sum, 16, 64);
            sum += __shfl_xor(sum, 32, 64);
            if ((nt & 3) == g) oval = sum + b2v;
            if ((nt & 3) == 3)
                out[(size_t)t * HWSZ + blockpx + (nt >> 2) * 64 + lane] = oval;
        }
    }
}

// ---- fallback (no workspace): round-2-style kernel, params from global
__global__ __launch_bounds__(256) void mask_head_mfma_nows(
    const float* __restrict__ x,
    const float* __restrict__ params,
    const int*   __restrict__ num_ins,
    float*       __restrict__ out,
    int N, int T)
{
    const int tid  = threadIdx.x;
    const int wave = tid >> 6;
    const int lane = tid & 63;
    const int col  = lane & 15;
    const int g    = lane >> 4;
    const int n    = blockIdx.y;
    const int pxw  = blockIdx.x * 256 + wave * 64;

    int t0 = 0;
    for (int j = 0; j < n; ++j) t0 += num_ins[j];
    int t1 = t0 + num_ins[n];
    if (n == N - 1) t1 = T;
    if (t1 > T) t1 = T;

    BF8 xb[4][2];
    const float* xbase = x + (size_t)n * CIN * HWSZ + pxw + col;
#pragma unroll
    for (int nt = 0; nt < 4; ++nt)
#pragma unroll
        for (int c = 0; c < 2; ++c)
#pragma unroll
            for (int j = 0; j < 8; ++j)
                xb[nt][c].b[j] = (__bf16)xbase[(size_t)(c * 32 + g * 8 + j) * HWSZ + nt * 16];

    float xf[4], yf[4];
#pragma unroll
    for (int nt = 0; nt < 4; ++nt) {
        const int pix = pxw + nt * 16 + col;
        xf[nt] = (float)(pix & (WW - 1));
        yf[nt] = (float)(pix >> 8);
    }

    for (int t = t0; t < t1; ++t) {
        const float* pw = params + (size_t)t * PP;
        BF8 a00, a01, a1;
#pragma unroll
        for (int j = 0; j < 8; ++j) {
            a00.b[j] = (__bf16)pw[col * 66 + 2 +      g * 8 + j];
            a01.b[j] = (__bf16)pw[col * 66 + 2 + 32 + g * 8 + j];
        }
#pragma unroll
        for (int j = 0; j < 4; ++j) {
            a1.b[j]     = (__bf16)pw[1056 + col * 16 + g * 4 + j];
            a1.b[4 + j] = (__bf16)0.f;
        }
        float wxv[4], wyv[4], b0v[4], b1v[4], w2v[4];
#pragma unroll
        for (int j = 0; j < 4; ++j) {
            const int r = g * 4 + j;
            wxv[j] = pw[r * 66 + 0];
            wyv[j] = pw[r * 66 + 1];
            b0v[j] = pw[1328 + r];
            b1v[j] = pw[1344 + r];
            w2v[j] = pw[1312 + r];
        }
        const float b2v = pw[1360] - MASK_BIAS_SHIFT;

        f32x4 acc0[4];
#pragma unroll
        for (int nt = 0; nt < 4; ++nt) {
            f32x4 a = {0.f, 0.f, 0.f, 0.f};
            a = __builtin_amdgcn_mfma_f32_16x16x32_bf16(a00.s, xb[nt][0].s, a, 0, 0, 0);
            a = __builtin_amdgcn_mfma_f32_16x16x32_bf16(a01.s, xb[nt][1].s, a, 0, 0, 0);
            acc0[nt] = a;
        }
        BF8 h0[4];
#pragma unroll
        for (int nt = 0; nt < 4; ++nt)
#pragma unroll
            for (int j = 0; j < 4; ++j) {
                float v = acc0[nt][j] + b0v[j];
                v = fmaf(wxv[j], xf[nt], v);
                v = fmaf(wyv[j], yf[nt], v);
                v = fmaxf(v, 0.f);
                h0[nt].b[j]     = (__bf16)v;
                h0[nt].b[4 + j] = (__bf16)0.f;
            }
        f32x4 acc1[4];
#pragma unroll
        for (int nt = 0; nt < 4; ++nt) {
            f32x4 a = {0.f, 0.f, 0.f, 0.f};
            acc1[nt] = __builtin_amdgcn_mfma_f32_16x16x32_bf16(a1.s, h0[nt].s, a, 0, 0, 0);
        }
        float oval = 0.f;
#pragma unroll
        for (int nt = 0; nt < 4; ++nt) {
            float sum = 0.f;
#pragma unroll
            for (int j = 0; j < 4; ++j) {
                const float h = fmaxf(acc1[nt][j] + b1v[j], 0.f);
                sum = fmaf(w2v[j], h, sum);
            }
            sum += __shfl_xor(sum, 16, 64);
            sum += __shfl_xor(sum, 32, 64);
            if (nt == g) oval = sum + b2v;
        }
        out[(size_t)t * HWSZ + pxw + lane] = oval;
    }
}

extern "C" void kernel_launch(void* const* d_in, const int* in_sizes, int n_in,
                              void* d_out, int out_size, void* d_ws, size_t ws_size,
                              hipStream_t stream) {
    const float* x      = (const float*)d_in[0];
    const float* params = (const float*)d_in[1];
    const int*   nins   = (const int*)d_in[2];
    float*       out    = (float*)d_out;

    const int N = in_sizes[2];            // images
    const int T = in_sizes[1] / PP;       // total instances (param rows)
    const size_t ws_needed = (size_t)T * PKF * sizeof(float);

    if (ws_size >= ws_needed) {
        float* pk = (float*)d_ws;
        prep_params<<<T, dim3(64), 0, stream>>>(params, pk);
        dim3 grid(HH, N, NSPLIT);         // 160 row-blocks x 4 images x split
        mask_head_lds<<<grid, dim3(256), 0, stream>>>(x, pk, nins, out, N, T);
    } else {
        dim3 grid(HWSZ / 256, N);
        mask_head_mfma_nows<<<grid, dim3(256), 0, stream>>>(x, params, nins, out, N, T);
    }
}

// Round 5
// 31.166 us; speedup vs baseline: 2.0975x; 2.0975x over previous
//
#include <hip/hip_runtime.h>

// DynamicMaskHead, all-MFMA formulation (round 5).
// Per (instance, 16-px tile): acc0 = W0x·X + coordMFMA(wx,wy,b0 hi/lo channels)
//   h0 = relu(acc0) -> layer1 MFMA (b1 as bias channel) -> h1 = relu ->
//   layer2 MFMA with row-replicated w2 => every lane holds the pixel answer,
//   lane keeps tile nt==g => zero cross-lane shuffles, coalesced store.
// K-consistency fragment trick + C/D layout (col=lane&15,row=(l>>4)*4+j)
// verified rounds 2-4 (absmax 0.03125). xf<=255, yf<=159 are EXACT in bf16;
// coord/bias weights enter as hi/lo bf16 splits (~2^-16 rel error).

#define CIN  64
#define HH   160
#define WW   256
#define HWSZ (HH * WW)
#define PP   1361
#define MASK_BIAS_SHIFT 2.19f
#define PKF  1344              // floats per instance in packed buffer (5376 B)
#define NSPLIT 2               // instance split across gridDim.z

typedef short short8 __attribute__((ext_vector_type(8)));
typedef float f32x4  __attribute__((ext_vector_type(4)));

union BF8 { short8 s; __bf16 b[8]; };

__device__ inline __bf16 bhi(float v) { return (__bf16)v; }
__device__ inline __bf16 blo(float v) { return (__bf16)(v - (float)(__bf16)v); }

// packed float offsets per instance:
//   0: a00 (W0 x-ch 0..31)   256: a01 (x-ch 32..63)   512: a1b (W1 + b1 ch)
//   768: a2r (replicated w2) 1024: ca (coord/b0 ch)   1280: b2 (scalar)

__global__ __launch_bounds__(64) void prep_params(
    const float* __restrict__ params, float* __restrict__ pk)
{
    const int t    = blockIdx.x;
    const int lane = threadIdx.x;
    const int col  = lane & 15;
    const int g    = lane >> 4;
    const float* pw = params + (size_t)t * PP;
    float* dst = pk + (size_t)t * PKF;

    const __bf16 z = (__bf16)0.f;

    BF8 a00, a01;
#pragma unroll
    for (int j = 0; j < 8; ++j) {
        a00.b[j] = (__bf16)pw[col * 66 + 2 +      g * 8 + j];
        a01.b[j] = (__bf16)pw[col * 66 + 2 + 32 + g * 8 + j];
    }

    BF8 a1b;                                   // W1 (k=0..15) + b1 bias channel
#pragma unroll
    for (int j = 0; j < 4; ++j)
        a1b.b[j] = (__bf16)pw[1056 + col * 16 + g * 4 + j];
    {
        const float b1 = pw[1344 + col];
        a1b.b[4] = (g == 0) ? bhi(b1) : z;
        a1b.b[5] = (g == 0) ? blo(b1) : z;
        a1b.b[6] = z;  a1b.b[7] = z;
    }

    BF8 a2r;                                   // w2 replicated across rows
#pragma unroll
    for (int j = 0; j < 4; ++j) a2r.b[j] = (__bf16)pw[1312 + g * 4 + j];
    a2r.b[4] = z; a2r.b[5] = z; a2r.b[6] = z; a2r.b[7] = z;

    BF8 ca;                                    // [wx_hi,wx_lo,wy_hi,wy_lo,b0_hi,b0_lo,0,0] on g==0
    {
        const float wx = pw[col * 66 + 0];
        const float wy = pw[col * 66 + 1];
        const float b0 = pw[1328 + col];
        ca.b[0] = (g == 0) ? bhi(wx) : z;
        ca.b[1] = (g == 0) ? blo(wx) : z;
        ca.b[2] = (g == 0) ? bhi(wy) : z;
        ca.b[3] = (g == 0) ? blo(wy) : z;
        ca.b[4] = (g == 0) ? bhi(b0) : z;
        ca.b[5] = (g == 0) ? blo(b0) : z;
        ca.b[6] = z; ca.b[7] = z;
    }

    ((short8*)(dst       ))[lane] = a00.s;
    ((short8*)(dst +  256))[lane] = a01.s;
    ((short8*)(dst +  512))[lane] = a1b.s;
    ((short8*)(dst +  768))[lane] = a2r.s;
    ((short8*)(dst + 1024))[lane] = ca.s;
    if (lane == 0) dst[1280] = pw[1360] - MASK_BIAS_SHIFT;
}

__global__ __launch_bounds__(256, 4) void mask_head_v5(
    const float* __restrict__ x,
    const float* __restrict__ pk,
    const int*   __restrict__ num_ins,
    float*       __restrict__ out,
    int N, int T)
{
    const int tid  = threadIdx.x;
    const int wave = tid >> 6;
    const int lane = tid & 63;
    const int col  = lane & 15;
    const int g    = lane >> 4;
    const int n    = blockIdx.y;
    const int s    = blockIdx.z;
    const int pxw  = blockIdx.x * 256 + wave * 64;

    int t0 = 0;
    for (int j = 0; j < n; ++j) t0 += num_ins[j];
    int t1 = t0 + num_ins[n];
    if (n == N - 1) t1 = T;
    if (t1 > T) t1 = T;
    t0 = __builtin_amdgcn_readfirstlane(t0);
    t1 = __builtin_amdgcn_readfirstlane(t1);

    // x fragments: 64 px x 64 ch, loaded once, reused by all instances
    BF8 xb[4][2];
    const float* xbase = x + (size_t)n * CIN * HWSZ + pxw + col;
#pragma unroll
    for (int nt = 0; nt < 4; ++nt)
#pragma unroll
        for (int c = 0; c < 2; ++c)
#pragma unroll
            for (int j = 0; j < 8; ++j) {
                const int ch = c * 32 + g * 8 + j;
                xb[nt][c].b[j] = (__bf16)xbase[(size_t)ch * HWSZ + nt * 16];
            }

    // coordinate B-fragments (instance-independent): [xf,xf,yf,yf,1,1,0,0]
    BF8 b2c[4];
#pragma unroll
    for (int nt = 0; nt < 4; ++nt) {
        const int px = pxw + nt * 16 + col;
        const __bf16 xfb = (__bf16)(float)(px & (WW - 1));
        const __bf16 yfb = (__bf16)(float)(px >> 8);
        b2c[nt].b[0] = xfb; b2c[nt].b[1] = xfb;
        b2c[nt].b[2] = yfb; b2c[nt].b[3] = yfb;
        b2c[nt].b[4] = (__bf16)1.f; b2c[nt].b[5] = (__bf16)1.f;
        b2c[nt].b[6] = (__bf16)0.f; b2c[nt].b[7] = (__bf16)0.f;
    }

    const __bf16 one = (__bf16)1.f, zero = (__bf16)0.f;

    for (int t = t0 + s; t < t1; t += NSPLIT) {
        const float* pt = pk + (size_t)t * PKF;

        short8 a00 = ((const short8*)(pt       ))[lane];
        short8 a01 = ((const short8*)(pt +  256))[lane];
        short8 a1b = ((const short8*)(pt +  512))[lane];
        short8 a2r = ((const short8*)(pt +  768))[lane];
        short8 ca  = ((const short8*)(pt + 1024))[lane];
        const float b2v = pt[1280];

        float oval = 0.f;
#pragma unroll
        for (int nt = 0; nt < 4; ++nt) {
            // layer 0: coords/b0 + x-channels, all in one fp32 accumulator
            f32x4 acc0 = {0.f, 0.f, 0.f, 0.f};
            acc0 = __builtin_amdgcn_mfma_f32_16x16x32_bf16(ca,  b2c[nt].s,  acc0, 0, 0, 0);
            acc0 = __builtin_amdgcn_mfma_f32_16x16x32_bf16(a00, xb[nt][0].s, acc0, 0, 0, 0);
            acc0 = __builtin_amdgcn_mfma_f32_16x16x32_bf16(a01, xb[nt][1].s, acc0, 0, 0, 0);

            BF8 h0;
#pragma unroll
            for (int j = 0; j < 4; ++j) h0.b[j] = (__bf16)fmaxf(acc0[j], 0.f);
            h0.b[4] = one; h0.b[5] = one; h0.b[6] = zero; h0.b[7] = zero;

            // layer 1 (b1 enters via bias channel)
            f32x4 acc1 = {0.f, 0.f, 0.f, 0.f};
            acc1 = __builtin_amdgcn_mfma_f32_16x16x32_bf16(a1b, h0.s, acc1, 0, 0, 0);

            BF8 h1;
#pragma unroll
            for (int j = 0; j < 4; ++j) h1.b[j] = (__bf16)fmaxf(acc1[j], 0.f);
            h1.b[4] = zero; h1.b[5] = zero; h1.b[6] = zero; h1.b[7] = zero;

            // layer 2: row-replicated w2 -> every lane holds the answer
            f32x4 acc2 = {0.f, 0.f, 0.f, 0.f};
            acc2 = __builtin_amdgcn_mfma_f32_16x16x32_bf16(a2r, h1.s, acc2, 0, 0, 0);

            if (nt == g) oval = acc2[0] + b2v;   // lane's own pixel, no shuffle
        }
        out[(size_t)t * HWSZ + pxw + lane] = oval;
    }
}

// ---- fallback (no workspace): round-2-style kernel, params from global
__global__ __launch_bounds__(256) void mask_head_mfma_nows(
    const float* __restrict__ x,
    const float* __restrict__ params,
    const int*   __restrict__ num_ins,
    float*       __restrict__ out,
    int N, int T)
{
    const int tid  = threadIdx.x;
    const int wave = tid >> 6;
    const int lane = tid & 63;
    const int col  = lane & 15;
    const int g    = lane >> 4;
    const int n    = blockIdx.y;
    const int pxw  = blockIdx.x * 256 + wave * 64;

    int t0 = 0;
    for (int j = 0; j < n; ++j) t0 += num_ins[j];
    int t1 = t0 + num_ins[n];
    if (n == N - 1) t1 = T;
    if (t1 > T) t1 = T;

    BF8 xb[4][2];
    const float* xbase = x + (size_t)n * CIN * HWSZ + pxw + col;
#pragma unroll
    for (int nt = 0; nt < 4; ++nt)
#pragma unroll
        for (int c = 0; c < 2; ++c)
#pragma unroll
            for (int j = 0; j < 8; ++j)
                xb[nt][c].b[j] = (__bf16)xbase[(size_t)(c * 32 + g * 8 + j) * HWSZ + nt * 16];

    float xf[4], yf[4];
#pragma unroll
    for (int nt = 0; nt < 4; ++nt) {
        const int pix = pxw + nt * 16 + col;
        xf[nt] = (float)(pix & (WW - 1));
        yf[nt] = (float)(pix >> 8);
    }

    for (int t = t0; t < t1; ++t) {
        const float* pw = params + (size_t)t * PP;
        BF8 a00, a01, a1;
#pragma unroll
        for (int j = 0; j < 8; ++j) {
            a00.b[j] = (__bf16)pw[col * 66 + 2 +      g * 8 + j];
            a01.b[j] = (__bf16)pw[col * 66 + 2 + 32 + g * 8 + j];
        }
#pragma unroll
        for (int j = 0; j < 4; ++j) {
            a1.b[j]     = (__bf16)pw[1056 + col * 16 + g * 4 + j];
            a1.b[4 + j] = (__bf16)0.f;
        }
        float wxv[4], wyv[4], b0v[4], b1v[4], w2v[4];
#pragma unroll
        for (int j = 0; j < 4; ++j) {
            const int r = g * 4 + j;
            wxv[j] = pw[r * 66 + 0];
            wyv[j] = pw[r * 66 + 1];
            b0v[j] = pw[1328 + r];
            b1v[j] = pw[1344 + r];
            w2v[j] = pw[1312 + r];
        }
        const float b2v = pw[1360] - MASK_BIAS_SHIFT;

        f32x4 acc0[4];
#pragma unroll
        for (int nt = 0; nt < 4; ++nt) {
            f32x4 a = {0.f, 0.f, 0.f, 0.f};
            a = __builtin_amdgcn_mfma_f32_16x16x32_bf16(a00.s, xb[nt][0].s, a, 0, 0, 0);
            a = __builtin_amdgcn_mfma_f32_16x16x32_bf16(a01.s, xb[nt][1].s, a, 0, 0, 0);
            acc0[nt] = a;
        }
        BF8 h0[4];
#pragma unroll
        for (int nt = 0; nt < 4; ++nt)
#pragma unroll
            for (int j = 0; j < 4; ++j) {
                float v = acc0[nt][j] + b0v[j];
                v = fmaf(wxv[j], xf[nt], v);
                v = fmaf(wyv[j], yf[nt], v);
                v = fmaxf(v, 0.f);
                h0[nt].b[j]     = (__bf16)v;
                h0[nt].b[4 + j] = (__bf16)0.f;
            }
        f32x4 acc1[4];
#pragma unroll
        for (int nt = 0; nt < 4; ++nt) {
            f32x4 a = {0.f, 0.f, 0.f, 0.f};
            acc1[nt] = __builtin_amdgcn_mfma_f32_16x16x32_bf16(a1.s, h0[nt].s, a, 0, 0, 0);
        }
        float oval = 0.f;
#pragma unroll
        for (int nt = 0; nt < 4; ++nt) {
            float sum = 0.f;
#pragma unroll
            for (int j = 0; j < 4; ++j) {
                const float h = fmaxf(acc1[nt][j] + b1v[j], 0.f);
                sum = fmaf(w2v[j], h, sum);
            }
            sum += __shfl_xor(sum, 16, 64);
            sum += __shfl_xor(sum, 32, 64);
            if (nt == g) oval = sum + b2v;
        }
        out[(size_t)t * HWSZ + pxw + lane] = oval;
    }
}

extern "C" void kernel_launch(void* const* d_in, const int* in_sizes, int n_in,
                              void* d_out, int out_size, void* d_ws, size_t ws_size,
                              hipStream_t stream) {
    const float* x      = (const float*)d_in[0];
    const float* params = (const float*)d_in[1];
    const int*   nins   = (const int*)d_in[2];
    float*       out    = (float*)d_out;

    const int N = in_sizes[2];            // images
    const int T = in_sizes[1] / PP;       // total instances (param rows)
    const size_t ws_needed = (size_t)T * PKF * sizeof(float);

    if (ws_size >= ws_needed) {
        float* pk = (float*)d_ws;
        prep_params<<<T, dim3(64), 0, stream>>>(params, pk);
        dim3 grid(HWSZ / 256, N, NSPLIT);
        mask_head_v5<<<grid, dim3(256), 0, stream>>>(x, pk, nins, out, N, T);
    } else {
        dim3 grid(HWSZ / 256, N);
        mask_head_mfma_nows<<<grid, dim3(256), 0, stream>>>(x, params, nins, out, N, T);
    }
}